// Round 3
// baseline (495.709 us; speedup 1.0000x reference)
//
#include <hip/hip_runtime.h>
#include <hip/hip_bf16.h>
#include <stdint.h>
#include <stddef.h>

#define DI __device__ __forceinline__

typedef unsigned short u16;
typedef float f32x4 __attribute__((ext_vector_type(4)));
typedef short bf16x8 __attribute__((ext_vector_type(8)));
typedef u16 u16x4 __attribute__((ext_vector_type(4)));

constexpr int Mm = 8192;
constexpr int Dd = 1024;
constexpr float LOG2E = 1.44269504088896f;

DI u16 bf(float f) {
  __hip_bfloat16 h = __float2bfloat16(f);
  return *reinterpret_cast<u16*>(&h);
}

DI float b2f(short s) {
  union { float f; unsigned u; } v;
  v.u = ((unsigned)(unsigned short)s) << 16;
  return v.f;
}

DI f32x4 mfma16(bf16x8 a, bf16x8 b, f32x4 c) {
  return __builtin_amdgcn_mfma_f32_16x16x32_bf16(a, b, c, 0, 0, 0);
}

DI void gload16(const u16* g, u16* l) {
  __builtin_amdgcn_global_load_lds(
      (const __attribute__((address_space(1))) void*)(g),
      (__attribute__((address_space(3))) void*)(l), 16, 0, 0);
}

// ---------------- convert x (f32 -> bf16), 4 elems/thread ----------------
__global__ __launch_bounds__(256) void k_cvt(const float* __restrict__ x,
                                             u16* __restrict__ o) {
  size_t i = (size_t)blockIdx.x * 256 + threadIdx.x;
  float4 v = *(const float4*)(x + i * 4);
  u16x4 r;
  r.x = bf(v.x); r.y = bf(v.y); r.z = bf(v.z); r.w = bf(v.w);
  *(u16x4*)(o + i * 4) = r;
}

// ---------------- pb (f32) -> bf16 * LOG2E ----------------
__global__ __launch_bounds__(256) void k_pb(const float* __restrict__ pb,
                                            u16* __restrict__ pbb) {
  size_t i = (size_t)blockIdx.x * 256 + threadIdx.x;
  float4 v = *(const float4*)(pb + i * 4);
  u16x4 r;
  r.x = bf(v.x * LOG2E); r.y = bf(v.y * LOG2E);
  r.z = bf(v.z * LOG2E); r.w = bf(v.w * LOG2E);
  *(u16x4*)(pbb + i * 4) = r;
}

// ---------------- transpose 1024x1024 f32 W -> bf16 WT[n][k] ----------------
__global__ __launch_bounds__(256) void k_tr(const float* __restrict__ W,
                                            u16* __restrict__ WT) {
  __shared__ float t[32][33];
  int bx = blockIdx.x * 32;  // k block
  int by = blockIdx.y * 32;  // n block
  int tx = threadIdx.x, ty = threadIdx.y;  // (32,8)
#pragma unroll
  for (int i = 0; i < 4; ++i)
    t[ty + i * 8][tx] = W[(size_t)(bx + ty + i * 8) * 1024 + by + tx];
  __syncthreads();
#pragma unroll
  for (int i = 0; i < 4; ++i)
    WT[(size_t)(by + ty + i * 8) * 1024 + bx + tx] = bf(t[tx][ty + i * 8]);
}

// ---------------- GEMM (m97 structure): C[M,1024] = A @ WT^T ----------------
// MODE 0: Q  -> bf16 (acc+bias)*0.125*log2e, [m][d]
// MODE 1: K  -> bf16 acc+bias,               [m][d]
// MODE 2: V  -> bf16 acc+bias, transposed    [b][d][seq] (LDS-transposed store)
// MODE 3: O  -> f32 acc+bias+resid,          [m][d]
template <int MODE>
__global__ __launch_bounds__(256) void k_gemm(const u16* __restrict__ A,
                                              const u16* __restrict__ WT,
                                              const float* __restrict__ bias,
                                              const float* __restrict__ resid,
                                              void* __restrict__ outp) {
  __shared__ __align__(16) u16 smem[2 * 128 * 64];  // As | Bs, 32 KB
  u16* As = smem;
  u16* Bs = smem + 128 * 64;
  const int tid = threadIdx.x;
  const int lane = tid & 63;
  const int wave = tid >> 6;
  const int brow = blockIdx.y * 128;
  const int bcol = blockIdx.x * 128;
  const int wr = (wave >> 1) * 64;
  const int wc = (wave & 1) * 64;
  const int l15 = lane & 15, l4 = lane >> 4;

  f32x4 acc[4][4] = {};
  const int crow0 = tid >> 3;        // chunk row for r=0
  const int kpos = (tid & 7) * 8;    // k offset within row

  for (int t = 0; t < 16; ++t) {
    const int k0 = t * 64;
#pragma unroll
    for (int r = 0; r < 4; ++r) {
      int crow = r * 32 + crow0;
      u16* ldsbase_a = As + ((r * 256 + wave * 64) << 3);  // wave-uniform
      u16* ldsbase_b = Bs + ((r * 256 + wave * 64) << 3);
      gload16(A + (size_t)(brow + crow) * 1024 + k0 + kpos, ldsbase_a);
      gload16(WT + (size_t)(bcol + crow) * 1024 + k0 + kpos, ldsbase_b);
    }
    __syncthreads();
#pragma unroll
    for (int kk = 0; kk < 2; ++kk) {
      bf16x8 af[4], bg[4];
      const int kb = kk * 32 + l4 * 8;
#pragma unroll
      for (int mt = 0; mt < 4; ++mt)
        af[mt] = *(const bf16x8*)(As + (wr + mt * 16 + l15) * 64 + kb);
#pragma unroll
      for (int nt = 0; nt < 4; ++nt)
        bg[nt] = *(const bf16x8*)(Bs + (wc + nt * 16 + l15) * 64 + kb);
#pragma unroll
      for (int mt = 0; mt < 4; ++mt)
#pragma unroll
        for (int nt = 0; nt < 4; ++nt)
          acc[mt][nt] = mfma16(af[mt], bg[nt], acc[mt][nt]);
    }
    __syncthreads();
  }

  if (MODE == 2) {
    // transpose through LDS: vts[d_local 128][seq_local 128] bf16, XOR-swizzled
#pragma unroll
    for (int nt = 0; nt < 4; ++nt) {
      int dl = wc + nt * 16 + l15;
      float bv = bias[bcol + dl];
#pragma unroll
      for (int mt = 0; mt < 4; ++mt) {
        int s4 = wr + mt * 16 + l4 * 4;
        u16x4 pk;
        pk.x = bf(acc[mt][nt][0] + bv);
        pk.y = bf(acc[mt][nt][1] + bv);
        pk.z = bf(acc[mt][nt][2] + bv);
        pk.w = bf(acc[mt][nt][3] + bv);
        *(u16x4*)(smem + dl * 128 + (s4 ^ ((dl & 7) << 3))) = pk;
      }
    }
    __syncthreads();
    const int bb = brow >> 10;        // batch
    const int seq0 = brow & 1023;
    const int chunk = tid & 15;
#pragma unroll
    for (int p = 0; p < 8; ++p) {
      int dl = p * 16 + (tid >> 4);
      bf16x8 v = *(const bf16x8*)(smem + dl * 128 + ((chunk * 8) ^ ((dl & 7) << 3)));
      *(bf16x8*)((u16*)outp + ((size_t)bb * 1024 + bcol + dl) * 1024 + seq0 + chunk * 8) = v;
    }
    return;
  }

  // epilogue. C/D: col = lane&15, row = (lane>>4)*4 + i
#pragma unroll
  for (int nt = 0; nt < 4; ++nt) {
    int gc = bcol + wc + nt * 16 + l15;
    float bv = bias[gc];
#pragma unroll
    for (int mt = 0; mt < 4; ++mt) {
#pragma unroll
      for (int i = 0; i < 4; ++i) {
        int gm = brow + wr + mt * 16 + l4 * 4 + i;
        float v = acc[mt][nt][i] + bv;
        if (MODE == 0) {
          ((u16*)outp)[(size_t)gm * 1024 + gc] = bf(v * (0.125f * LOG2E));
        } else if (MODE == 1) {
          ((u16*)outp)[(size_t)gm * 1024 + gc] = bf(v);
        } else {
          ((float*)outp)[(size_t)gm * 1024 + gc] = v + resid[(size_t)gm * 1024 + gc];
        }
      }
    }
  }
}

// ---------------- attention: per (b,h), 32 q-rows, 512 threads ----------------
// q [m][d] bf16 (pre-scaled log2e/8), k [m][d] bf16, vt [b][d][seq] bf16,
// pbb [n][n] bf16 (pre-scaled log2e)
__global__ __launch_bounds__(512, 4) void k_attn(const u16* __restrict__ q,
                                                 const u16* __restrict__ kk_,
                                                 const u16* __restrict__ vt,
                                                 const u16* __restrict__ pbb,
                                                 float* __restrict__ attn_out,
                                                 u16* __restrict__ aout) {
  __shared__ __align__(16) u16 sp[32 * 1024];  // 64 KB bf16 scores/P
  __shared__ float invbuf[32];
  const int tid = threadIdx.x;
  const int lane = tid & 63;
  const int wave = tid >> 6;        // 0..7
  // XCD-chunked swizzle: 4096 blocks = 8 XCD chunks of 512
  const int bid = blockIdx.x;
  const int swz = (bid & 7) * 512 + (bid >> 3);
  const int bh = swz >> 5;          // 0..127
  const int q0 = (swz & 31) * 32;
  const int b = bh >> 4, h = bh & 15;
  const int l15 = lane & 15, l4 = lane >> 4;

  // ---- phase 1: S^T fragments = K Q^T (A=K, B=Q) + pb -> bf16 LDS ----
  bf16x8 qf[2][2];
#pragma unroll
  for (int qs = 0; qs < 2; ++qs) {
    const u16* qp = q + ((size_t)(b * 1024 + q0 + qs * 16 + l15)) * 1024 + h * 64 + l4 * 8;
    qf[qs][0] = *(const bf16x8*)qp;
    qf[qs][1] = *(const bf16x8*)(qp + 32);
  }
  const int colbase = wave * 128;
#pragma unroll 2
  for (int nt = 0; nt < 8; ++nt) {
    const int col = colbase + nt * 16 + l15;
    const u16* kp = kk_ + ((size_t)(b * 1024 + col)) * 1024 + h * 64 + l4 * 8;
    bf16x8 k0 = *(const bf16x8*)kp;
    bf16x8 k1 = *(const bf16x8*)(kp + 32);
    f32x4 cc[2] = {};
#pragma unroll
    for (int qs = 0; qs < 2; ++qs) {
      cc[qs] = mfma16(k0, qf[qs][0], cc[qs]);
      cc[qs] = mfma16(k1, qf[qs][1], cc[qs]);
    }
    const int c4 = colbase + nt * 16 + l4 * 4;  // k-col group for this lane
#pragma unroll
    for (int qs = 0; qs < 2; ++qs) {
      const int qrow = q0 + qs * 16 + l15;
      u16x4 pbv = *(const u16x4*)(pbb + (size_t)qrow * 1024 + c4);
      u16x4 pk;
      pk.x = bf(cc[qs][0] + b2f((short)pbv.x));
      pk.y = bf(cc[qs][1] + b2f((short)pbv.y));
      pk.z = bf(cc[qs][2] + b2f((short)pbv.z));
      pk.w = bf(cc[qs][3] + b2f((short)pbv.w));
      const int lrow = qs * 16 + l15;
      *(u16x4*)(sp + lrow * 1024 + (c4 ^ ((lrow & 7) << 3))) = pk;
    }
  }
  __syncthreads();

  // ---- phase 2: softmax, 16 threads/row, values held in registers ----
  {
    const int r = tid >> 4;         // 0..31
    const int l = tid & 15;
    const int rx = (r & 7) << 3;
    u16* rowp = sp + r * 1024;
    bf16x8 R[8];
#pragma unroll
    for (int g = 0; g < 8; ++g)
      R[g] = *(const bf16x8*)(rowp + ((g * 128 + l * 8) ^ rx));
    float mx = -3e38f;
#pragma unroll
    for (int g = 0; g < 8; ++g)
#pragma unroll
      for (int j = 0; j < 8; ++j) mx = fmaxf(mx, b2f(R[g][j]));
#pragma unroll
    for (int o = 1; o < 16; o <<= 1) mx = fmaxf(mx, __shfl_xor(mx, o));
    float sum = 0.f;
#pragma unroll
    for (int g = 0; g < 8; ++g) {
      bf16x8 e;
#pragma unroll
      for (int j = 0; j < 8; ++j) {
        float t = __builtin_amdgcn_exp2f(b2f(R[g][j]) - mx);
        sum += t;
        e[j] = (short)bf(t);
      }
      R[g] = e;
      *(bf16x8*)(rowp + ((g * 128 + l * 8) ^ rx)) = e;  // unnormalized P for PV
    }
#pragma unroll
    for (int o = 1; o < 16; o <<= 1) sum += __shfl_xor(sum, o);
    float inv = 1.f / sum;
    if (l == 0) invbuf[r] = inv;
    float* gout = attn_out + ((size_t)bh * 1024 + q0 + r) * 1024;
#pragma unroll
    for (int g = 0; g < 8; ++g) {
      float4 w0, w1;
      w0.x = b2f(R[g][0]) * inv; w0.y = b2f(R[g][1]) * inv;
      w0.z = b2f(R[g][2]) * inv; w0.w = b2f(R[g][3]) * inv;
      w1.x = b2f(R[g][4]) * inv; w1.y = b2f(R[g][5]) * inv;
      w1.z = b2f(R[g][6]) * inv; w1.w = b2f(R[g][7]) * inv;
      *(float4*)(gout + g * 128 + l * 8) = w0;
      *(float4*)(gout + g * 128 + l * 8 + 4) = w1;
    }
  }
  __syncthreads();

  // ---- phase 3: PV (unnormalized P), wave: row-half (w&1), kv (w>>1)*256 ----
  f32x4 pacc[4] = {};
  const int rh = wave & 1;
  const int kvb = (wave >> 1) * 256;
  const int prow = rh * 16 + l15;
  const u16* vbase = vt + ((size_t)b * 1024 + h * 64) * 1024;
#pragma unroll 2
  for (int ks = 0; ks < 8; ++ks) {
    const int c0 = kvb + ks * 32 + l4 * 8;
    bf16x8 pf = *(const bf16x8*)(sp + prow * 1024 + (c0 ^ ((l15 & 7) << 3)));
#pragma unroll
    for (int nt = 0; nt < 4; ++nt) {
      bf16x8 vf = *(const bf16x8*)(vbase + (size_t)(nt * 16 + l15) * 1024 + c0);
      pacc[nt] = mfma16(pf, vf, pacc[nt]);
    }
  }
  __syncthreads();

  // ---- phase 4: k-split reduce (4 partials), scale by inv, write aout ----
  float* red = (float*)(void*)sp;   // [4][32][64] f32 = 32 KB
  const int kvg = wave >> 1;
#pragma unroll
  for (int nt = 0; nt < 4; ++nt)
#pragma unroll
    for (int i = 0; i < 4; ++i)
      red[kvg * 2048 + (rh * 16 + l4 * 4 + i) * 64 + nt * 16 + l15] = pacc[nt][i];
  __syncthreads();
#pragma unroll
  for (int it = 0; it < 4; ++it) {
    int o = it * 512 + tid;
    int row = o >> 6, d = o & 63;
    float s = (red[row * 64 + d] + red[2048 + row * 64 + d] +
               red[4096 + row * 64 + d] + red[6144 + row * 64 + d]) * invbuf[row];
    aout[(size_t)(b * 1024 + q0 + row) * 1024 + h * 64 + d] = bf(s);
  }
}

// ---------------- LayerNorm: one wave per row ----------------
__global__ __launch_bounds__(256) void k_ln(const float* __restrict__ y,
                                            const float* __restrict__ g,
                                            const float* __restrict__ be,
                                            float* __restrict__ o) {
  const int lane = threadIdx.x & 63;
  const int wave = threadIdx.x >> 6;
  size_t row = (size_t)blockIdx.x * 4 + wave;
  const float* yr = y + row * 1024;
  float4 v[4];
  float s = 0.f, sq = 0.f;
#pragma unroll
  for (int i = 0; i < 4; ++i) {
    v[i] = *(const float4*)(yr + i * 256 + lane * 4);
    s += v[i].x + v[i].y + v[i].z + v[i].w;
    sq += v[i].x * v[i].x + v[i].y * v[i].y + v[i].z * v[i].z + v[i].w * v[i].w;
  }
#pragma unroll
  for (int off = 1; off < 64; off <<= 1) {
    s += __shfl_xor(s, off);
    sq += __shfl_xor(sq, off);
  }
  float mu = s * (1.f / 1024.f);
  float var = sq * (1.f / 1024.f) - mu * mu;
  float rs = rsqrtf(fmaxf(var, 0.f) + 1e-5f);
  float* orow = o + row * 1024;
#pragma unroll
  for (int i = 0; i < 4; ++i) {
    int c = i * 256 + lane * 4;
    float4 gg = *(const float4*)(g + c);
    float4 bb = *(const float4*)(be + c);
    float4 r;
    r.x = (v[i].x - mu) * rs * gg.x + bb.x;
    r.y = (v[i].y - mu) * rs * gg.y + bb.y;
    r.z = (v[i].z - mu) * rs * gg.z + bb.z;
    r.w = (v[i].w - mu) * rs * gg.w + bb.w;
    *(float4*)(orow + c) = r;
  }
}

extern "C" void kernel_launch(void* const* d_in, const int* in_sizes, int n_in,
                              void* d_out, int out_size, void* d_ws, size_t ws_size,
                              hipStream_t stream) {
  const float* x = (const float*)d_in[0];
  const float* Wq = (const float*)d_in[1];
  const float* bq = (const float*)d_in[2];
  const float* Wk = (const float*)d_in[3];
  const float* bk = (const float*)d_in[4];
  const float* Wv = (const float*)d_in[5];
  const float* bv = (const float*)d_in[6];
  const float* pb = (const float*)d_in[7];
  const float* Wo = (const float*)d_in[8];
  const float* bo = (const float*)d_in[9];
  const float* gamma = (const float*)d_in[10];
  const float* beta = (const float*)d_in[11];

  char* ws = (char*)d_ws;
  u16* xb = (u16*)(ws);            // 16MB, reused as aows after V gemm
  u16* aows = (u16*)(ws);
  u16* wqT = (u16*)(ws + (16u << 20));   // reused as pbb after Q gemm
  u16* pbb = (u16*)(ws + (16u << 20));
  u16* wkT = (u16*)(ws + (18u << 20));
  u16* wvT = (u16*)(ws + (20u << 20));
  u16* woT = (u16*)(ws + (22u << 20));
  u16* qws = (u16*)(ws + (24u << 20));
  u16* kws = (u16*)(ws + (40u << 20));
  u16* vtws = (u16*)(ws + (56u << 20));
  float* yws = (float*)(ws + (72u << 20));

  float* out_ln = (float*)d_out;
  float* out_attn = out_ln + (size_t)Mm * Dd;

  k_cvt<<<8192, 256, 0, stream>>>(x, xb);
  k_tr<<<dim3(32, 32), dim3(32, 8), 0, stream>>>(Wq, wqT);
  k_tr<<<dim3(32, 32), dim3(32, 8), 0, stream>>>(Wk, wkT);
  k_tr<<<dim3(32, 32), dim3(32, 8), 0, stream>>>(Wv, wvT);
  k_tr<<<dim3(32, 32), dim3(32, 8), 0, stream>>>(Wo, woT);
  k_gemm<0><<<dim3(8, 64), 256, 0, stream>>>(xb, wqT, bq, nullptr, qws);
  k_pb<<<1024, 256, 0, stream>>>(pb, pbb);   // overlays wqT (dead after Q gemm)
  k_gemm<1><<<dim3(8, 64), 256, 0, stream>>>(xb, wkT, bk, nullptr, kws);
  k_gemm<2><<<dim3(8, 64), 256, 0, stream>>>(xb, wvT, bv, nullptr, vtws);
  k_attn<<<4096, 512, 0, stream>>>(qws, kws, vtws, pbb, out_attn, aows);
  k_gemm<3><<<dim3(8, 64), 256, 0, stream>>>(aows, woT, bo, x, yws);
  k_ln<<<2048, 256, 0, stream>>>(yws, gamma, beta, out_ln);
}

// Round 5
// 495.400 us; speedup vs baseline: 1.0006x; 1.0006x over previous
//
#include <hip/hip_runtime.h>
#include <hip/hip_bf16.h>
#include <stdint.h>
#include <stddef.h>

#define DI __device__ __forceinline__

typedef unsigned short u16;
typedef float f32x4 __attribute__((ext_vector_type(4)));
typedef short bf16x8 __attribute__((ext_vector_type(8)));
typedef u16 u16x4 __attribute__((ext_vector_type(4)));

constexpr int Mm = 8192;
constexpr int Dd = 1024;
constexpr float LOG2E = 1.44269504088896f;

DI u16 bf(float f) {
  __hip_bfloat16 h = __float2bfloat16(f);
  return *reinterpret_cast<u16*>(&h);
}

DI float b2f(short s) {
  union { float f; unsigned u; } v;
  v.u = ((unsigned)(unsigned short)s) << 16;
  return v.f;
}

DI f32x4 mfma16(bf16x8 a, bf16x8 b, f32x4 c) {
  return __builtin_amdgcn_mfma_f32_16x16x32_bf16(a, b, c, 0, 0, 0);
}

DI void gload16(const u16* g, u16* l) {
  __builtin_amdgcn_global_load_lds(
      (const __attribute__((address_space(1))) void*)(g),
      (__attribute__((address_space(3))) void*)(l), 16, 0, 0);
}

// ---------------- convert x (f32 -> bf16), 4 elems/thread ----------------
__global__ __launch_bounds__(256) void k_cvt(const float* __restrict__ x,
                                             u16* __restrict__ o) {
  size_t i = (size_t)blockIdx.x * 256 + threadIdx.x;
  float4 v = *(const float4*)(x + i * 4);
  u16x4 r;
  r.x = bf(v.x); r.y = bf(v.y); r.z = bf(v.z); r.w = bf(v.w);
  *(u16x4*)(o + i * 4) = r;
}

// ---------------- pb (f32) -> bf16 * LOG2E ----------------
__global__ __launch_bounds__(256) void k_pb(const float* __restrict__ pb,
                                            u16* __restrict__ pbb) {
  size_t i = (size_t)blockIdx.x * 256 + threadIdx.x;
  float4 v = *(const float4*)(pb + i * 4);
  u16x4 r;
  r.x = bf(v.x * LOG2E); r.y = bf(v.y * LOG2E);
  r.z = bf(v.z * LOG2E); r.w = bf(v.w * LOG2E);
  *(u16x4*)(pbb + i * 4) = r;
}

// ---------------- transpose 4x (1024x1024 f32 W -> bf16 WT[n][k]) ----------------
__global__ __launch_bounds__(256) void k_tr4(const float* __restrict__ W0,
                                             const float* __restrict__ W1,
                                             const float* __restrict__ W2,
                                             const float* __restrict__ W3,
                                             u16* __restrict__ T0,
                                             u16* __restrict__ T1,
                                             u16* __restrict__ T2,
                                             u16* __restrict__ T3) {
  __shared__ float t[32][33];
  const float* W;
  u16* T;
  switch (blockIdx.z) {
    case 0: W = W0; T = T0; break;
    case 1: W = W1; T = T1; break;
    case 2: W = W2; T = T2; break;
    default: W = W3; T = T3; break;
  }
  int bx = blockIdx.x * 32;  // k block
  int by = blockIdx.y * 32;  // n block
  int tx = threadIdx.x, ty = threadIdx.y;  // (32,8)
#pragma unroll
  for (int i = 0; i < 4; ++i)
    t[ty + i * 8][tx] = W[(size_t)(bx + ty + i * 8) * 1024 + by + tx];
  __syncthreads();
#pragma unroll
  for (int i = 0; i < 4; ++i)
    T[(size_t)(by + ty + i * 8) * 1024 + bx + tx] = bf(t[tx][ty + i * 8]);
}

// ---------------- GEMM (m97 structure): C[M,1024] = A @ WT^T ----------------
// MODE 0: Q  -> bf16 (acc+bias)*0.125*log2e, [m][d]
// MODE 1: K  -> bf16 acc+bias,               [m][d]
// MODE 2: V  -> bf16 acc+bias, transposed    [b][d][seq] (LDS-transposed store)
// MODE 3: O  -> f32 acc+bias+resid,          [m][d]
template <int MODE>
__global__ __launch_bounds__(256) void k_gemm(const u16* __restrict__ A,
                                              const u16* __restrict__ WT,
                                              const float* __restrict__ bias,
                                              const float* __restrict__ resid,
                                              void* __restrict__ outp) {
  __shared__ __align__(16) u16 smem[2 * 128 * 64];  // As | Bs, 32 KB
  u16* As = smem;
  u16* Bs = smem + 128 * 64;
  const int tid = threadIdx.x;
  const int lane = tid & 63;
  const int wave = tid >> 6;
  const int brow = blockIdx.y * 128;
  const int bcol = blockIdx.x * 128;
  const int wr = (wave >> 1) * 64;
  const int wc = (wave & 1) * 64;
  const int l15 = lane & 15, l4 = lane >> 4;

  f32x4 acc[4][4] = {};
  const int crow0 = tid >> 3;        // chunk row for r=0
  const int kpos = (tid & 7) * 8;    // k offset within row

  for (int t = 0; t < 16; ++t) {
    const int k0 = t * 64;
#pragma unroll
    for (int r = 0; r < 4; ++r) {
      int crow = r * 32 + crow0;
      u16* ldsbase_a = As + ((r * 256 + wave * 64) << 3);  // wave-uniform
      u16* ldsbase_b = Bs + ((r * 256 + wave * 64) << 3);
      gload16(A + (size_t)(brow + crow) * 1024 + k0 + kpos, ldsbase_a);
      gload16(WT + (size_t)(bcol + crow) * 1024 + k0 + kpos, ldsbase_b);
    }
    __syncthreads();
#pragma unroll
    for (int kk = 0; kk < 2; ++kk) {
      bf16x8 af[4], bg[4];
      const int kb = kk * 32 + l4 * 8;
#pragma unroll
      for (int mt = 0; mt < 4; ++mt)
        af[mt] = *(const bf16x8*)(As + (wr + mt * 16 + l15) * 64 + kb);
#pragma unroll
      for (int nt = 0; nt < 4; ++nt)
        bg[nt] = *(const bf16x8*)(Bs + (wc + nt * 16 + l15) * 64 + kb);
#pragma unroll
      for (int mt = 0; mt < 4; ++mt)
#pragma unroll
        for (int nt = 0; nt < 4; ++nt)
          acc[mt][nt] = mfma16(af[mt], bg[nt], acc[mt][nt]);
    }
    __syncthreads();
  }

  if (MODE == 2) {
    // transpose through LDS: [d_local 128][seq_local 128] bf16, XOR-swizzled
#pragma unroll
    for (int nt = 0; nt < 4; ++nt) {
      int dl = wc + nt * 16 + l15;
      float bv = bias[bcol + dl];
#pragma unroll
      for (int mt = 0; mt < 4; ++mt) {
        int s4 = wr + mt * 16 + l4 * 4;
        u16x4 pk;
        pk.x = bf(acc[mt][nt][0] + bv);
        pk.y = bf(acc[mt][nt][1] + bv);
        pk.z = bf(acc[mt][nt][2] + bv);
        pk.w = bf(acc[mt][nt][3] + bv);
        *(u16x4*)(smem + dl * 128 + (s4 ^ ((dl & 7) << 3))) = pk;
      }
    }
    __syncthreads();
    const int bb = brow >> 10;        // batch
    const int seq0 = brow & 1023;
    const int chunk = tid & 15;
#pragma unroll
    for (int p = 0; p < 8; ++p) {
      int dl = p * 16 + (tid >> 4);
      bf16x8 v = *(const bf16x8*)(smem + dl * 128 + ((chunk * 8) ^ ((dl & 7) << 3)));
      *(bf16x8*)((u16*)outp + ((size_t)bb * 1024 + bcol + dl) * 1024 + seq0 + chunk * 8) = v;
    }
    return;
  }

  // epilogue. C/D: col = lane&15, row = (lane>>4)*4 + i
#pragma unroll
  for (int nt = 0; nt < 4; ++nt) {
    int gc = bcol + wc + nt * 16 + l15;
    float bv = bias[gc];
#pragma unroll
    for (int mt = 0; mt < 4; ++mt) {
#pragma unroll
      for (int i = 0; i < 4; ++i) {
        int gm = brow + wr + mt * 16 + l4 * 4 + i;
        float v = acc[mt][nt][i] + bv;
        if (MODE == 0) {
          ((u16*)outp)[(size_t)gm * 1024 + gc] = bf(v * (0.125f * LOG2E));
        } else if (MODE == 1) {
          ((u16*)outp)[(size_t)gm * 1024 + gc] = bf(v);
        } else {
          ((float*)outp)[(size_t)gm * 1024 + gc] = v + resid[(size_t)gm * 1024 + gc];
        }
      }
    }
  }
}

// ---------------- attention: per (b,h), 16 q-rows, 256 threads ----------------
// Drain-free structure: 2 LDS-only barriers; ALL global stores after last barrier.
// q [m][d] bf16 (pre-scaled log2e/8), k [m][d] bf16, vt [b][d][seq] bf16,
// pbb [n][n] bf16 (pre-scaled log2e)
__global__ __launch_bounds__(256, 5) void k_attn(const u16* __restrict__ q,
                                                 const u16* __restrict__ kk_,
                                                 const u16* __restrict__ vt,
                                                 const u16* __restrict__ pbb,
                                                 float* __restrict__ attn_out,
                                                 u16* __restrict__ aout) {
  __shared__ __align__(16) u16 sp[16 * 1024];  // 32 KB P (bf16, row-XOR-swizzled)
  const int tid = threadIdx.x;
  const int lane = tid & 63;
  const int wave = tid >> 6;        // 0..3
  // XCD-chunked swizzle: 8192 blocks, 1024/XCD -> 16 bh per XCD (K,V stay in L2)
  const int bid = blockIdx.x;
  const int swz = (bid & 7) * 1024 + (bid >> 3);
  const int bh = swz >> 6;          // 0..127
  const int q0 = (swz & 63) * 16;
  const int b = bh >> 4, h = bh & 15;
  const int l15 = lane & 15, l4 = lane >> 4;

  // ---- P1: S^T = K·Q^T + pb -> bf16 LDS (swapped operands: C col = q) ----
  bf16x8 qf0, qf1;
  {
    const u16* qp = q + ((size_t)(b * 1024 + q0 + l15)) * 1024 + h * 64 + l4 * 8;
    qf0 = *(const bf16x8*)qp;
    qf1 = *(const bf16x8*)(qp + 32);
  }
  const int colbase = wave * 256;   // kv quarter per wave
#pragma unroll 4
  for (int nt = 0; nt < 16; ++nt) {
    const int col = colbase + nt * 16 + l15;
    const u16* kp = kk_ + ((size_t)(b * 1024 + col)) * 1024 + h * 64 + l4 * 8;
    bf16x8 k0 = *(const bf16x8*)kp;
    bf16x8 k1 = *(const bf16x8*)(kp + 32);
    f32x4 cc = {};
    cc = mfma16(k0, qf0, cc);
    cc = mfma16(k1, qf1, cc);
    const int c4 = colbase + nt * 16 + l4 * 4;   // kv index group
    u16x4 pbv = *(const u16x4*)(pbb + (size_t)(q0 + l15) * 1024 + c4);
    u16x4 pk;
    pk.x = bf(cc[0] + b2f((short)pbv.x));
    pk.y = bf(cc[1] + b2f((short)pbv.y));
    pk.z = bf(cc[2] + b2f((short)pbv.z));
    pk.w = bf(cc[3] + b2f((short)pbv.w));
    *(u16x4*)(sp + l15 * 1024 + (c4 ^ ((l15 & 7) << 3))) = pk;
  }
  __syncthreads();   // LDS-only drain (no global stores pending)

  // ---- P2: softmax, 16 thr/row, LDS gets NORMALIZED bf16 P ----
  const int r = tid >> 4;
  const int l = tid & 15;
  const int rx = (r & 7) << 3;
  u16* rowp = sp + r * 1024;
  bf16x8 R[8];
  float inv;
  {
#pragma unroll
    for (int g = 0; g < 8; ++g)
      R[g] = *(const bf16x8*)(rowp + ((g * 128 + l * 8) ^ rx));
    float mx = -3e38f;
#pragma unroll
    for (int g = 0; g < 8; ++g)
#pragma unroll
      for (int j = 0; j < 8; ++j) mx = fmaxf(mx, b2f(R[g][j]));
#pragma unroll
    for (int o = 1; o < 16; o <<= 1) mx = fmaxf(mx, __shfl_xor(mx, o));
    float sum = 0.f;
#pragma unroll
    for (int g = 0; g < 8; ++g) {
      bf16x8 e;
#pragma unroll
      for (int j = 0; j < 8; ++j) {
        float t = exp2f(b2f(R[g][j]) - mx);
        sum += t;
        e[j] = (short)bf(t);
      }
      R[g] = e;   // unnormalized exp, kept for tail store
    }
#pragma unroll
    for (int o = 1; o < 16; o <<= 1) sum += __shfl_xor(sum, o);
    inv = 1.f / sum;
#pragma unroll
    for (int g = 0; g < 8; ++g) {
      bf16x8 e;
#pragma unroll
      for (int j = 0; j < 8; ++j) e[j] = (short)bf(b2f(R[g][j]) * inv);
      *(bf16x8*)(rowp + ((g * 128 + l * 8) ^ rx)) = e;
    }
  }
  __syncthreads();   // LDS-only drain

  // ---- P3: PV, d-split across waves (no reduce, no further barrier) ----
  f32x4 oacc = {};
  const u16* vbase = vt + ((size_t)(b * 1024 + h * 64 + wave * 16 + l15)) * 1024;
  const int prx = (l15 & 7) << 3;
  const u16* prow = sp + l15 * 1024;
#pragma unroll 8
  for (int ks = 0; ks < 32; ++ks) {
    const int c0 = ks * 32 + l4 * 8;
    bf16x8 pf = *(const bf16x8*)(prow + (c0 ^ prx));   // A: P[q=l15][kv]
    bf16x8 vf = *(const bf16x8*)(vbase + c0);          // B: V^T[d][kv]
    oacc = mfma16(pf, vf, oacc);
  }

  // ---- tail: all global stores (drain only at wave end) ----
#pragma unroll
  for (int i = 0; i < 4; ++i)
    aout[(size_t)(b * 1024 + q0 + l4 * 4 + i) * 1024 + h * 64 + wave * 16 + l15] =
        bf(oacc[i]);

  {
    float* gout = attn_out + ((size_t)bh * 1024 + q0 + r) * 1024 + l * 8;
#pragma unroll
    for (int g = 0; g < 8; ++g) {
      f32x4 w0, w1;
      w0[0] = b2f(R[g][0]) * inv; w0[1] = b2f(R[g][1]) * inv;
      w0[2] = b2f(R[g][2]) * inv; w0[3] = b2f(R[g][3]) * inv;
      w1[0] = b2f(R[g][4]) * inv; w1[1] = b2f(R[g][5]) * inv;
      w1[2] = b2f(R[g][6]) * inv; w1[3] = b2f(R[g][7]) * inv;
      __builtin_nontemporal_store(w0, (f32x4*)(gout + g * 128));
      __builtin_nontemporal_store(w1, (f32x4*)(gout + g * 128 + 4));
    }
  }
}

// ---------------- LayerNorm: one wave per row ----------------
__global__ __launch_bounds__(256) void k_ln(const float* __restrict__ y,
                                            const float* __restrict__ g,
                                            const float* __restrict__ be,
                                            float* __restrict__ o) {
  const int lane = threadIdx.x & 63;
  const int wave = threadIdx.x >> 6;
  size_t row = (size_t)blockIdx.x * 4 + wave;
  const float* yr = y + row * 1024;
  float4 v[4];
  float s = 0.f, sq = 0.f;
#pragma unroll
  for (int i = 0; i < 4; ++i) {
    v[i] = *(const float4*)(yr + i * 256 + lane * 4);
    s += v[i].x + v[i].y + v[i].z + v[i].w;
    sq += v[i].x * v[i].x + v[i].y * v[i].y + v[i].z * v[i].z + v[i].w * v[i].w;
  }
#pragma unroll
  for (int off = 1; off < 64; off <<= 1) {
    s += __shfl_xor(s, off);
    sq += __shfl_xor(sq, off);
  }
  float mu = s * (1.f / 1024.f);
  float var = sq * (1.f / 1024.f) - mu * mu;
  float rs = rsqrtf(fmaxf(var, 0.f) + 1e-5f);
  float* orow = o + row * 1024;
#pragma unroll
  for (int i = 0; i < 4; ++i) {
    int c = i * 256 + lane * 4;
    float4 gg = *(const float4*)(g + c);
    float4 bb = *(const float4*)(be + c);
    float4 rr;
    rr.x = (v[i].x - mu) * rs * gg.x + bb.x;
    rr.y = (v[i].y - mu) * rs * gg.y + bb.y;
    rr.z = (v[i].z - mu) * rs * gg.z + bb.z;
    rr.w = (v[i].w - mu) * rs * gg.w + bb.w;
    *(float4*)(orow + c) = rr;
  }
}

extern "C" void kernel_launch(void* const* d_in, const int* in_sizes, int n_in,
                              void* d_out, int out_size, void* d_ws, size_t ws_size,
                              hipStream_t stream) {
  const float* x = (const float*)d_in[0];
  const float* Wq = (const float*)d_in[1];
  const float* bq = (const float*)d_in[2];
  const float* Wk = (const float*)d_in[3];
  const float* bk = (const float*)d_in[4];
  const float* Wv = (const float*)d_in[5];
  const float* bv = (const float*)d_in[6];
  const float* pb = (const float*)d_in[7];
  const float* Wo = (const float*)d_in[8];
  const float* bo = (const float*)d_in[9];
  const float* gamma = (const float*)d_in[10];
  const float* beta = (const float*)d_in[11];

  char* ws = (char*)d_ws;
  u16* xb = (u16*)(ws);            // 16MB, reused as aows after V gemm
  u16* aows = (u16*)(ws);
  u16* wqT = (u16*)(ws + (16u << 20));   // reused as pbb after Q gemm
  u16* pbb = (u16*)(ws + (16u << 20));
  u16* wkT = (u16*)(ws + (18u << 20));
  u16* wvT = (u16*)(ws + (20u << 20));
  u16* woT = (u16*)(ws + (22u << 20));
  u16* qws = (u16*)(ws + (24u << 20));
  u16* kws = (u16*)(ws + (40u << 20));
  u16* vtws = (u16*)(ws + (56u << 20));
  float* yws = (float*)(ws + (72u << 20));

  float* out_ln = (float*)d_out;
  float* out_attn = out_ln + (size_t)Mm * Dd;

  k_cvt<<<8192, 256, 0, stream>>>(x, xb);
  k_tr4<<<dim3(32, 32, 4), dim3(32, 8), 0, stream>>>(Wq, Wk, Wv, Wo, wqT, wkT, wvT, woT);
  k_gemm<0><<<dim3(8, 64), 256, 0, stream>>>(xb, wqT, bq, nullptr, qws);
  k_pb<<<1024, 256, 0, stream>>>(pb, pbb);   // overlays wqT (dead after Q gemm)
  k_gemm<1><<<dim3(8, 64), 256, 0, stream>>>(xb, wkT, bk, nullptr, kws);
  k_gemm<2><<<dim3(8, 64), 256, 0, stream>>>(xb, wvT, bv, nullptr, vtws);
  k_attn<<<8192, 256, 0, stream>>>(qws, kws, vtws, pbb, out_attn, aows);
  k_gemm<3><<<dim3(8, 64), 256, 0, stream>>>(aows, woT, bo, x, yws);
  k_ln<<<2048, 256, 0, stream>>>(yws, gamma, beta, out_ln);
}

// Round 6
// 356.182 us; speedup vs baseline: 1.3917x; 1.3909x over previous
//
#include <hip/hip_runtime.h>
#include <hip/hip_bf16.h>
#include <stdint.h>
#include <stddef.h>

#define DI __device__ __forceinline__

typedef unsigned short u16;
typedef float f32x4 __attribute__((ext_vector_type(4)));
typedef short bf16x8 __attribute__((ext_vector_type(8)));
typedef u16 u16x4 __attribute__((ext_vector_type(4)));

constexpr int Mm = 8192;
constexpr int Dd = 1024;
constexpr float LOG2E = 1.44269504088896f;

DI u16 bf(float f) {
  __hip_bfloat16 h = __float2bfloat16(f);
  return *reinterpret_cast<u16*>(&h);
}

DI float b2f(short s) {
  union { float f; unsigned u; } v;
  v.u = ((unsigned)(unsigned short)s) << 16;
  return v.f;
}

DI f32x4 mfma16(bf16x8 a, bf16x8 b, f32x4 c) {
  return __builtin_amdgcn_mfma_f32_16x16x32_bf16(a, b, c, 0, 0, 0);
}

DI void gload16(const u16* g, u16* l) {
  __builtin_amdgcn_global_load_lds(
      (const __attribute__((address_space(1))) void*)(g),
      (__attribute__((address_space(3))) void*)(l), 16, 0, 0);
}

// ---------------- convert x (f32 -> bf16), 4 elems/thread ----------------
__global__ __launch_bounds__(256) void k_cvt(const float* __restrict__ x,
                                             u16* __restrict__ o) {
  size_t i = (size_t)blockIdx.x * 256 + threadIdx.x;
  float4 v = *(const float4*)(x + i * 4);
  u16x4 r;
  r.x = bf(v.x); r.y = bf(v.y); r.z = bf(v.z); r.w = bf(v.w);
  *(u16x4*)(o + i * 4) = r;
}

// ---------------- pb (f32) -> bf16 * LOG2E ----------------
__global__ __launch_bounds__(256) void k_pb(const float* __restrict__ pb,
                                            u16* __restrict__ pbb) {
  size_t i = (size_t)blockIdx.x * 256 + threadIdx.x;
  float4 v = *(const float4*)(pb + i * 4);
  u16x4 r;
  r.x = bf(v.x * LOG2E); r.y = bf(v.y * LOG2E);
  r.z = bf(v.z * LOG2E); r.w = bf(v.w * LOG2E);
  *(u16x4*)(pbb + i * 4) = r;
}

// ---------------- transpose 4x (1024x1024 f32 W -> bf16 WT[n][k]) ----------------
__global__ __launch_bounds__(256) void k_tr4(const float* __restrict__ W0,
                                             const float* __restrict__ W1,
                                             const float* __restrict__ W2,
                                             const float* __restrict__ W3,
                                             u16* __restrict__ T0,
                                             u16* __restrict__ T1,
                                             u16* __restrict__ T2,
                                             u16* __restrict__ T3) {
  __shared__ float t[32][33];
  const float* W;
  u16* T;
  switch (blockIdx.z) {
    case 0: W = W0; T = T0; break;
    case 1: W = W1; T = T1; break;
    case 2: W = W2; T = T2; break;
    default: W = W3; T = T3; break;
  }
  int bx = blockIdx.x * 32;  // k block
  int by = blockIdx.y * 32;  // n block
  int tx = threadIdx.x, ty = threadIdx.y;  // (32,8)
#pragma unroll
  for (int i = 0; i < 4; ++i)
    t[ty + i * 8][tx] = W[(size_t)(bx + ty + i * 8) * 1024 + by + tx];
  __syncthreads();
#pragma unroll
  for (int i = 0; i < 4; ++i)
    T[(size_t)(by + ty + i * 8) * 1024 + bx + tx] = bf(t[tx][ty + i * 8]);
}

// ---------------- GEMM (m97 structure): C[M,1024] = A @ WT^T ----------------
// MODE 0: Q  -> bf16 (acc+bias)*0.125*log2e, [m][d]
// MODE 1: K  -> bf16 acc+bias,               [m][d]
// MODE 2: V  -> bf16 acc+bias, transposed    [b][d][seq] (LDS-transposed store)
// MODE 3: O  -> f32 acc+bias+resid,          [m][d]
template <int MODE>
__global__ __launch_bounds__(256) void k_gemm(const u16* __restrict__ A,
                                              const u16* __restrict__ WT,
                                              const float* __restrict__ bias,
                                              const float* __restrict__ resid,
                                              void* __restrict__ outp) {
  __shared__ __align__(16) u16 smem[2 * 128 * 64];  // As | Bs, 32 KB
  u16* As = smem;
  u16* Bs = smem + 128 * 64;
  const int tid = threadIdx.x;
  const int lane = tid & 63;
  const int wave = tid >> 6;
  const int brow = blockIdx.y * 128;
  const int bcol = blockIdx.x * 128;
  const int wr = (wave >> 1) * 64;
  const int wc = (wave & 1) * 64;
  const int l15 = lane & 15, l4 = lane >> 4;

  f32x4 acc[4][4] = {};
  const int crow0 = tid >> 3;        // chunk row for r=0
  const int kpos = (tid & 7) * 8;    // k offset within row

  for (int t = 0; t < 16; ++t) {
    const int k0 = t * 64;
#pragma unroll
    for (int r = 0; r < 4; ++r) {
      int crow = r * 32 + crow0;
      u16* ldsbase_a = As + ((r * 256 + wave * 64) << 3);  // wave-uniform
      u16* ldsbase_b = Bs + ((r * 256 + wave * 64) << 3);
      gload16(A + (size_t)(brow + crow) * 1024 + k0 + kpos, ldsbase_a);
      gload16(WT + (size_t)(bcol + crow) * 1024 + k0 + kpos, ldsbase_b);
    }
    __syncthreads();
#pragma unroll
    for (int kk = 0; kk < 2; ++kk) {
      bf16x8 af[4], bg[4];
      const int kb = kk * 32 + l4 * 8;
#pragma unroll
      for (int mt = 0; mt < 4; ++mt)
        af[mt] = *(const bf16x8*)(As + (wr + mt * 16 + l15) * 64 + kb);
#pragma unroll
      for (int nt = 0; nt < 4; ++nt)
        bg[nt] = *(const bf16x8*)(Bs + (wc + nt * 16 + l15) * 64 + kb);
#pragma unroll
      for (int mt = 0; mt < 4; ++mt)
#pragma unroll
        for (int nt = 0; nt < 4; ++nt)
          acc[mt][nt] = mfma16(af[mt], bg[nt], acc[mt][nt]);
    }
    __syncthreads();
  }

  if (MODE == 2) {
    // transpose through LDS: [d_local 128][seq_local 128] bf16, XOR-swizzled
#pragma unroll
    for (int nt = 0; nt < 4; ++nt) {
      int dl = wc + nt * 16 + l15;
      float bv = bias[bcol + dl];
#pragma unroll
      for (int mt = 0; mt < 4; ++mt) {
        int s4 = wr + mt * 16 + l4 * 4;
        u16x4 pk;
        pk.x = bf(acc[mt][nt][0] + bv);
        pk.y = bf(acc[mt][nt][1] + bv);
        pk.z = bf(acc[mt][nt][2] + bv);
        pk.w = bf(acc[mt][nt][3] + bv);
        *(u16x4*)(smem + dl * 128 + (s4 ^ ((dl & 7) << 3))) = pk;
      }
    }
    __syncthreads();
    const int bb = brow >> 10;        // batch
    const int seq0 = brow & 1023;
    const int chunk = tid & 15;
#pragma unroll
    for (int p = 0; p < 8; ++p) {
      int dl = p * 16 + (tid >> 4);
      bf16x8 v = *(const bf16x8*)(smem + dl * 128 + ((chunk * 8) ^ ((dl & 7) << 3)));
      *(bf16x8*)((u16*)outp + ((size_t)bb * 1024 + bcol + dl) * 1024 + seq0 + chunk * 8) = v;
    }
    return;
  }

  // epilogue. C/D: col = lane&15, row = (lane>>4)*4 + i
#pragma unroll
  for (int nt = 0; nt < 4; ++nt) {
    int gc = bcol + wc + nt * 16 + l15;
    float bv = bias[gc];
#pragma unroll
    for (int mt = 0; mt < 4; ++mt) {
#pragma unroll
      for (int i = 0; i < 4; ++i) {
        int gm = brow + wr + mt * 16 + l4 * 4 + i;
        float v = acc[mt][nt][i] + bv;
        if (MODE == 0) {
          ((u16*)outp)[(size_t)gm * 1024 + gc] = bf(v * (0.125f * LOG2E));
        } else if (MODE == 1) {
          ((u16*)outp)[(size_t)gm * 1024 + gc] = bf(v);
        } else {
          ((float*)outp)[(size_t)gm * 1024 + gc] = v + resid[(size_t)gm * 1024 + gc];
        }
      }
    }
  }
}

// ---------------- attention v6: per (b,h), 32 q-rows, 512 threads ----------------
// GEMM-shaped: K and V staged via global_load_lds (pre-swizzled source -> linear
// LDS dest -> XOR-swizzled ds_read). All global stores after last barrier.
// attn_out written lane-contiguous (1KB/wave-instruction).
__global__ __launch_bounds__(512) void k_attn(const u16* __restrict__ q,
                                              const u16* __restrict__ kk_,
                                              const u16* __restrict__ vt,
                                              const u16* __restrict__ pbb,
                                              float* __restrict__ attn_out,
                                              u16* __restrict__ aout) {
  __shared__ __align__(16) u16 sc[32 * 1024];   // 64 KB scores/P (XOR-swizzled)
  __shared__ __align__(16) u16 kst[128 * 64];   // 16 KB K/V stage (linear)
  const int tid = threadIdx.x;
  const int lane = tid & 63;
  const int wave = tid >> 6;        // 0..7
  // XCD-chunked swizzle: 4096 blocks = 8 chunks of 512 (4096%8==0, bijective)
  const int bid = blockIdx.x;
  const int swz = (bid & 7) * 512 + (bid >> 3);
  const int bh = swz >> 5;          // 0..127
  const int q0 = (swz & 31) * 32;
  const int b = bh >> 4, h = bh & 15;
  const int l15 = lane & 15, l4 = lane >> 4;

  // Q fragments (2 q-halves), held all kernel
  bf16x8 qf[2][2];
#pragma unroll
  for (int qs = 0; qs < 2; ++qs) {
    const u16* qp = q + ((size_t)(b * 1024 + q0 + qs * 16 + l15)) * 1024 + h * 64 + l4 * 8;
    qf[qs][0] = *(const bf16x8*)qp;
    qf[qs][1] = *(const bf16x8*)(qp + 32);
  }

  // ---- P1: S^T = K·Q^T + pb, 8 chunks of 128 kv, K DMA-staged ----
  for (int c = 0; c < 8; ++c) {
    // DMA K chunk: 128 kv rows x 64 d = 16 KB; source pre-swizzled (g ^ row&7)
#pragma unroll
    for (int rr = 0; rr < 2; ++rr) {
      int gru = rr * 512 + tid;
      int row = gru >> 3, g = gru & 7;
      int gsw = g ^ (row & 7);
      gload16(kk_ + (size_t)(b * 1024 + c * 128 + row) * 1024 + h * 64 + gsw * 8,
              kst + ((rr * 512 + wave * 64) << 3));
    }
    __syncthreads();   // DMA done (vmcnt drain)
    // compute: wave handles kv rows [wave*16, +16) of this chunk
    const int krow = wave * 16 + l15;
    bf16x8 k0 = *(const bf16x8*)(kst + krow * 64 + (((0 + l4) ^ (krow & 7)) << 3));
    bf16x8 k1 = *(const bf16x8*)(kst + krow * 64 + (((4 + l4) ^ (krow & 7)) << 3));
    const int c4 = c * 128 + wave * 16 + l4 * 4;   // kv elem group
#pragma unroll
    for (int qs = 0; qs < 2; ++qs) {
      f32x4 cc = {};
      cc = mfma16(k0, qf[qs][0], cc);
      cc = mfma16(k1, qf[qs][1], cc);
      const int lrow = qs * 16 + l15;              // q-local row
      u16x4 pbv = *(const u16x4*)(pbb + (size_t)(q0 + lrow) * 1024 + c4);
      u16x4 pk;
      pk.x = bf(cc[0] + b2f((short)pbv.x));
      pk.y = bf(cc[1] + b2f((short)pbv.y));
      pk.z = bf(cc[2] + b2f((short)pbv.z));
      pk.w = bf(cc[3] + b2f((short)pbv.w));
      *(u16x4*)(sc + lrow * 1024 + (c4 ^ ((lrow & 7) << 3))) = pk;
    }
    __syncthreads();   // kst free for next chunk
  }

  // prefetch V chunk 0 while softmax runs (kst free; drain at softmax barrier)
  {
#pragma unroll
    for (int rr = 0; rr < 2; ++rr) {
      int gru = rr * 512 + tid;
      int rd = gru >> 4, g = gru & 15;
      int gsw = g ^ (rd & 15);
      gload16(vt + (size_t)(b * 1024 + h * 64 + rd) * 1024 + 0 * 128 + gsw * 8,
              kst + ((rr * 512 + wave * 64) << 3));
    }
  }

  // ---- P2: softmax, 16 thr/row, normalized bf16 P back to LDS ----
  {
    const int r = tid >> 4;         // 0..31
    const int l = tid & 15;
    const int rx = (r & 7) << 3;
    u16* rowp = sc + r * 1024;
    bf16x8 R[8];
#pragma unroll
    for (int g = 0; g < 8; ++g)
      R[g] = *(const bf16x8*)(rowp + ((g * 128 + l * 8) ^ rx));
    float mx = -3e38f;
#pragma unroll
    for (int g = 0; g < 8; ++g)
#pragma unroll
      for (int j = 0; j < 8; ++j) mx = fmaxf(mx, b2f(R[g][j]));
#pragma unroll
    for (int o = 1; o < 16; o <<= 1) mx = fmaxf(mx, __shfl_xor(mx, o));
    float sum = 0.f;
    float e[8][8];
#pragma unroll
    for (int g = 0; g < 8; ++g)
#pragma unroll
      for (int j = 0; j < 8; ++j) {
        float t = exp2f(b2f(R[g][j]) - mx);
        e[g][j] = t;
        sum += t;
      }
#pragma unroll
    for (int o = 1; o < 16; o <<= 1) sum += __shfl_xor(sum, o);
    float inv = 1.f / sum;
#pragma unroll
    for (int g = 0; g < 8; ++g) {
      bf16x8 w;
#pragma unroll
      for (int j = 0; j < 8; ++j) w[j] = (short)bf(e[g][j] * inv);
      *(bf16x8*)(rowp + ((g * 128 + l * 8) ^ rx)) = w;
    }
  }
  __syncthreads();   // P normalized + V chunk 0 staged

  // ---- P3: PV, 8 chunks of 128 kv, V DMA-staged; wave = (qh, dq) ----
  f32x4 oacc = {};
  const int qh = wave & 1;          // q half
  const int dq = wave >> 1;         // d quarter
  const int prow = qh * 16 + l15;   // q-local row for A
  const int vrow = dq * 16 + l15;   // d row for B
  for (int c = 0; c < 8; ++c) {
#pragma unroll
    for (int ks = 0; ks < 4; ++ks) {
      const int gc = c * 16 + ks * 4 + l4;   // kv 16B-granule idx
      bf16x8 pf = *(const bf16x8*)(sc + prow * 1024 + ((gc ^ (prow & 7)) << 3));
      bf16x8 vf = *(const bf16x8*)(kst + vrow * 128 + (((ks * 4 + l4) ^ (vrow & 15)) << 3));
      oacc = mfma16(pf, vf, oacc);
    }
    __syncthreads();   // kst consumed
    if (c < 7) {
#pragma unroll
      for (int rr = 0; rr < 2; ++rr) {
        int gru = rr * 512 + tid;
        int rd = gru >> 4, g = gru & 15;
        int gsw = g ^ (rd & 15);
        gload16(vt + (size_t)(b * 1024 + h * 64 + rd) * 1024 + (c + 1) * 128 + gsw * 8,
                kst + ((rr * 512 + wave * 64) << 3));
      }
      __syncthreads(); // DMA done
    }
  }

  // ---- tail: all global stores ----
#pragma unroll
  for (int i = 0; i < 4; ++i)
    aout[(size_t)(b * 1024 + q0 + qh * 16 + l4 * 4 + i) * 1024 + h * 64 + dq * 16 + l15] =
        bf(oacc[i]);

  // attn_out: lane-contiguous f32x4 (1 KB per wave-instruction), from LDS P
#pragma unroll
  for (int it = 0; it < 16; ++it) {
    int idx = it * 512 + tid;
    int row = idx >> 8;            // 0..31
    int col4 = idx & 255;          // f32x4 index within row
    int ebase = (col4 * 4) ^ ((row & 7) << 3);
    u16x4 p = *(const u16x4*)(sc + row * 1024 + ebase);
    f32x4 w;
    w[0] = b2f((short)p.x); w[1] = b2f((short)p.y);
    w[2] = b2f((short)p.z); w[3] = b2f((short)p.w);
    __builtin_nontemporal_store(
        w, (f32x4*)(attn_out + ((size_t)bh * 1024 + q0 + row) * 1024 + col4 * 4));
  }
}

// ---------------- LayerNorm: one wave per row ----------------
__global__ __launch_bounds__(256) void k_ln(const float* __restrict__ y,
                                            const float* __restrict__ g,
                                            const float* __restrict__ be,
                                            float* __restrict__ o) {
  const int lane = threadIdx.x & 63;
  const int wave = threadIdx.x >> 6;
  size_t row = (size_t)blockIdx.x * 4 + wave;
  const float* yr = y + row * 1024;
  float4 v[4];
  float s = 0.f, sq = 0.f;
#pragma unroll
  for (int i = 0; i < 4; ++i) {
    v[i] = *(const float4*)(yr + i * 256 + lane * 4);
    s += v[i].x + v[i].y + v[i].z + v[i].w;
    sq += v[i].x * v[i].x + v[i].y * v[i].y + v[i].z * v[i].z + v[i].w * v[i].w;
  }
#pragma unroll
  for (int off = 1; off < 64; off <<= 1) {
    s += __shfl_xor(s, off);
    sq += __shfl_xor(sq, off);
  }
  float mu = s * (1.f / 1024.f);
  float var = sq * (1.f / 1024.f) - mu * mu;
  float rs = rsqrtf(fmaxf(var, 0.f) + 1e-5f);
  float* orow = o + row * 1024;
#pragma unroll
  for (int i = 0; i < 4; ++i) {
    int c = i * 256 + lane * 4;
    float4 gg = *(const float4*)(g + c);
    float4 bb = *(const float4*)(be + c);
    float4 rr;
    rr.x = (v[i].x - mu) * rs * gg.x + bb.x;
    rr.y = (v[i].y - mu) * rs * gg.y + bb.y;
    rr.z = (v[i].z - mu) * rs * gg.z + bb.z;
    rr.w = (v[i].w - mu) * rs * gg.w + bb.w;
    *(float4*)(orow + c) = rr;
  }
}

extern "C" void kernel_launch(void* const* d_in, const int* in_sizes, int n_in,
                              void* d_out, int out_size, void* d_ws, size_t ws_size,
                              hipStream_t stream) {
  const float* x = (const float*)d_in[0];
  const float* Wq = (const float*)d_in[1];
  const float* bq = (const float*)d_in[2];
  const float* Wk = (const float*)d_in[3];
  const float* bk = (const float*)d_in[4];
  const float* Wv = (const float*)d_in[5];
  const float* bv = (const float*)d_in[6];
  const float* pb = (const float*)d_in[7];
  const float* Wo = (const float*)d_in[8];
  const float* bo = (const float*)d_in[9];
  const float* gamma = (const float*)d_in[10];
  const float* beta = (const float*)d_in[11];

  char* ws = (char*)d_ws;
  u16* xb = (u16*)(ws);            // 16MB, reused as aows after V gemm
  u16* aows = (u16*)(ws);
  u16* wqT = (u16*)(ws + (16u << 20));   // reused as pbb after Q gemm
  u16* pbb = (u16*)(ws + (16u << 20));
  u16* wkT = (u16*)(ws + (18u << 20));
  u16* wvT = (u16*)(ws + (20u << 20));
  u16* woT = (u16*)(ws + (22u << 20));
  u16* qws = (u16*)(ws + (24u << 20));
  u16* kws = (u16*)(ws + (40u << 20));
  u16* vtws = (u16*)(ws + (56u << 20));
  float* yws = (float*)(ws + (72u << 20));

  float* out_ln = (float*)d_out;
  float* out_attn = out_ln + (size_t)Mm * Dd;

  k_cvt<<<8192, 256, 0, stream>>>(x, xb);
  k_tr4<<<dim3(32, 32, 4), dim3(32, 8), 0, stream>>>(Wq, Wk, Wv, Wo, wqT, wkT, wvT, woT);
  k_gemm<0><<<dim3(8, 64), 256, 0, stream>>>(xb, wqT, bq, nullptr, qws);
  k_pb<<<1024, 256, 0, stream>>>(pb, pbb);   // overlays wqT (dead after Q gemm)
  k_gemm<1><<<dim3(8, 64), 256, 0, stream>>>(xb, wkT, bk, nullptr, kws);
  k_gemm<2><<<dim3(8, 64), 256, 0, stream>>>(xb, wvT, bv, nullptr, vtws);
  k_attn<<<4096, 512, 0, stream>>>(qws, kws, vtws, pbb, out_attn, aows);
  k_gemm<3><<<dim3(8, 64), 256, 0, stream>>>(aows, woT, bo, x, yws);
  k_ln<<<2048, 256, 0, stream>>>(yws, gamma, beta, out_ln);
}